// Round 2
// baseline (2919.367 us; speedup 1.0000x reference)
//
#include <hip/hip_runtime.h>

typedef short bf16x8 __attribute__((ext_vector_type(8)));
typedef float f32x4 __attribute__((ext_vector_type(4)));

__device__ __forceinline__ float bf2f(unsigned short u) {
    union { unsigned int i; float f; } c; c.i = ((unsigned int)u) << 16; return c.f;
}
__device__ __forceinline__ unsigned short f2bf(float f) {
    union { float f; unsigned int i; } c; c.f = f;
    unsigned int u = c.i;
    u += 0x7fffu + ((u >> 16) & 1u);          // round-to-nearest-even
    return (unsigned short)(u >> 16);
}

// async global->LDS, 16B per lane; LDS dest must be wave-uniform base + lane*16
__device__ __forceinline__ void gload_lds16(const unsigned short* g, unsigned short* l) {
    __builtin_amdgcn_global_load_lds(
        (const __attribute__((address_space(1))) void*)g,
        (__attribute__((address_space(3))) void*)l, 16, 0, 0);
}

// ---------------------------------------------------------------------------
// fpn fp32 NCHW [4][256][160][160] -> bf16 NHWC padded [4][162][162][256]
__global__ void transpose_pad(const float* __restrict__ x, unsigned short* __restrict__ xpad) {
    int idx = blockIdx.x * 256 + threadIdx.x;       // 4*160*160*32 = 3,276,800 exact
    int w = idx % 160; int t = idx / 160;
    int cv = t % 32;   t /= 32;
    int h = t % 160;   int n = t / 160;
    const float* src = x + (((size_t)(n * 256 + cv * 8) * 160 + h) * 160 + w);
    unsigned short us[8];
#pragma unroll
    for (int k = 0; k < 8; ++k) us[k] = f2bf(src[(size_t)k * 25600]);
    uint4 o;
    o.x = (unsigned int)us[0] | ((unsigned int)us[1] << 16);
    o.y = (unsigned int)us[2] | ((unsigned int)us[3] << 16);
    o.z = (unsigned int)us[4] | ((unsigned int)us[5] << 16);
    o.w = (unsigned int)us[6] | ((unsigned int)us[7] << 16);
    *(uint4*)(xpad + ((size_t)((n * 162 + h + 1) * 162) + (w + 1)) * 256 + cv * 8) = o;
}

// zero the 1-wide border of a padded NHWC buffer [4][162][162][C]
__global__ void zero_borders(unsigned short* __restrict__ buf, int C) {
    int CV = C >> 3;
    int total = 4 * 644 * CV;
    int idx = blockIdx.x * 256 + threadIdx.x;
    if (idx >= total) return;
    int cv = idx % CV; int t = idx / CV;
    int p = t % 644;   int n = t / 644;
    int h, w;
    if (p < 162)      { h = 0;   w = p; }
    else if (p < 324) { h = 161; w = p - 162; }
    else { int q = p - 324; h = 1 + (q >> 1); w = (q & 1) ? 161 : 0; }
    uint4 z = make_uint4(0u, 0u, 0u, 0u);
    *(uint4*)(buf + ((size_t)((n * 162 + h) * 162) + w) * C + cv * 8) = z;
}

// w fp32 OIHW [CO][CI][3][3] -> bf16 [tap][CO][CI]
__global__ void pack_w(const float* __restrict__ w, unsigned short* __restrict__ out, int CO, int CI) {
    int idx = blockIdx.x * 256 + threadIdx.x;
    int tot = 9 * CO * CI;
    if (idx >= tot) return;
    int ci = idx % CI; int t = idx / CI;
    int co = t % CO;   int tap = t / CO;
    out[idx] = f2bf(w[((size_t)(co * CI + ci)) * 9 + tap]);
}

// ---------------------------------------------------------------------------
// 3x3 conv, implicit GEMM, bf16 MFMA 16x16x32, async LDS staging.
// Per ci-chunk (64): stage the 6x34 spatial halo ONCE (serves all 9 taps),
// then per tap stage only the 128x64 weight tile. All staging via
// global_load_lds width=16; XOR-16B swizzle folded into global source addr.
// LDS: Bs 224x64 (28.6KB, 204 used) + As 128x64 (16KB) = 44KB -> 3 blocks/CU.
template<int CI, int COT>
__global__ __launch_bounds__(256) void conv3x3_mfma(
        const unsigned short* __restrict__ xpad,
        const unsigned short* __restrict__ wpk,
        unsigned short* __restrict__ ypad,
        float* __restrict__ sum, float* __restrict__ sumsq) {
    __shared__ __align__(16) unsigned short Bs[224 * 64];
    __shared__ __align__(16) unsigned short As[128 * 64];

    const int tid = threadIdx.x;
    const int wv = tid >> 6, lane = tid & 63;
    const int quad = lane >> 4, l15 = lane & 15;
    const int wr = wv >> 1, wc = wv & 1;

    int bid = blockIdx.x;
    const int wt = bid % 5;  bid /= 5;
    const int ht = bid % 40; bid /= 40;
    const int n = bid % 4;
    const int co0 = (bid / 4) * 128;
    const int h0 = ht * 4, w0 = wt * 32;   // halo origin in padded coords

    f32x4 acc[4][4];
#pragma unroll
    for (int i = 0; i < 4; ++i)
#pragma unroll
        for (int j = 0; j < 4; ++j) acc[i][j] = (f32x4){0.f, 0.f, 0.f, 0.f};

    for (int ci0 = 0; ci0 < CI; ci0 += 64) {
        __syncthreads();   // prior chunk's MFMA reads of Bs/As complete
        // ---- stage B halo: 224 positions x 64ci (204 real, rest clamped)
        {
            const unsigned short* xbase = xpad + ((size_t)(n * 162 + h0) * 162 + w0) * CI + ci0;
#pragma unroll
            for (int c = 0; c < 7; ++c) {
                const int f = c * 4096 + tid * 16;       // byte offset into Bs
                int p = f >> 7; if (p > 203) p = 203;    // clamp tail (data unused)
                const int g = ((f >> 4) & 7) ^ (p & 7);  // logical 16B group
                const int ph = p / 34, pw = p - ph * 34;
                gload_lds16(xbase + ((size_t)(ph * 162 + pw)) * CI + g * 8,
                            (unsigned short*)Bs + (f >> 1));
            }
        }
#pragma unroll
        for (int dh = 0; dh < 3; ++dh) {
#pragma unroll
            for (int dw = 0; dw < 3; ++dw) {
                const int tap = dh * 3 + dw;
                if (tap) __syncthreads();   // prior tap's A reads complete
                // ---- stage A: weights [tap][co0..+128][ci0..+64]
                {
                    const unsigned short* wbase = wpk + ((size_t)(tap * COT + co0)) * CI + ci0;
#pragma unroll
                    for (int c = 0; c < 4; ++c) {
                        const int f = c * 4096 + tid * 16;
                        const int row = f >> 7;
                        const int g = ((f >> 4) & 7) ^ (row & 7);
                        gload_lds16(wbase + (size_t)row * CI + g * 8,
                                    (unsigned short*)As + (f >> 1));
                    }
                }
                __syncthreads();            // drains vmcnt: As/Bs ready
                const int toff = dh * 34 + dw;
#pragma unroll
                for (int s = 0; s < 2; ++s) {
                    const int g0 = s * 4 + quad;
                    bf16x8 a[4], b[4];
#pragma unroll
                    for (int i = 0; i < 4; ++i) {
                        int row = wr * 64 + i * 16 + l15;
                        a[i] = *(const bf16x8*)&As[row * 64 + ((g0 ^ (row & 7)) << 3)];
                    }
#pragma unroll
                    for (int j = 0; j < 4; ++j) {
                        int sp = wc * 64 + j * 16 + l15;
                        int p = (sp >> 5) * 34 + (sp & 31) + toff;
                        b[j] = *(const bf16x8*)&Bs[p * 64 + ((g0 ^ (p & 7)) << 3)];
                    }
#pragma unroll
                    for (int i = 0; i < 4; ++i)
#pragma unroll
                        for (int j = 0; j < 4; ++j)
                            acc[i][j] = __builtin_amdgcn_mfma_f32_16x16x32_bf16(a[i], b[j], acc[i][j], 0, 0, 0);
                }
            }
        }
    }

    // epilogue: store y (bf16, NHWC padded interior) + BN partial stats
#pragma unroll
    for (int i = 0; i < 4; ++i) {
        const int co_l = wr * 64 + i * 16 + quad * 4;
#pragma unroll
        for (int j = 0; j < 4; ++j) {
            const int sp = wc * 64 + j * 16 + l15;
            const int jh = sp >> 5, jw = sp & 31;
            f32x4 v = acc[i][j];
            ushort4 pk;
            pk.x = f2bf(v[0]); pk.y = f2bf(v[1]); pk.z = f2bf(v[2]); pk.w = f2bf(v[3]);
            *(ushort4*)(ypad + ((size_t)((n * 162 + h0 + jh + 1) * 162) + (w0 + jw + 1)) * COT
                        + co0 + co_l) = pk;
        }
#pragma unroll
        for (int r = 0; r < 4; ++r) {
            float s1 = 0.f, s2 = 0.f;
#pragma unroll
            for (int j = 0; j < 4; ++j) { float v = acc[i][j][r]; s1 += v; s2 += v * v; }
#pragma unroll
            for (int m = 1; m < 16; m <<= 1) {
                s1 += __shfl_xor(s1, m, 64);
                s2 += __shfl_xor(s2, m, 64);
            }
            if (l15 == 0) {
                atomicAdd(&sum[co0 + co_l + r], s1);
                atomicAdd(&sumsq[co0 + co_l + r], s2);
            }
        }
    }
}

// ---------------------------------------------------------------------------
__global__ void bn_finalize(const float* __restrict__ sum, const float* __restrict__ sumsq,
                            const float* __restrict__ g, const float* __restrict__ b,
                            float* __restrict__ scale, float* __restrict__ shift, int C) {
    int c = blockIdx.x * 256 + threadIdx.x;
    if (c >= C) return;
    const float inv = 1.0f / 102400.0f;
    float m = sum[c] * inv;
    float v = sumsq[c] * inv - m * m;
    float sc = g[c] * rsqrtf(v + 1e-5f);
    scale[c] = sc;
    shift[c] = b[c] - m * sc;
}

// in-place y := relu(y*scale[c]+shift[c]) over the interior of padded NHWC buf
template<int C>
__global__ void bn_apply(unsigned short* __restrict__ buf,
                         const float* __restrict__ scale, const float* __restrict__ shift) {
    constexpr int CV = C / 8;
    int idx = blockIdx.x * 256 + threadIdx.x;       // 4*25600*CV exact
    int cv = idx % CV; int pos = idx / CV;
    int w = pos % 160; int h = (pos / 160) % 160; int n = pos / 25600;
    unsigned short* p = buf + ((size_t)((n * 162 + h + 1) * 162) + (w + 1)) * C + cv * 8;
    uint4 v = *(const uint4*)p;
    unsigned int ua[4] = {v.x, v.y, v.z, v.w};
    unsigned int ob[4];
#pragma unroll
    for (int j = 0; j < 4; ++j) {
        int c = cv * 8 + j * 2;
        float f0 = bf2f((unsigned short)(ua[j] & 0xffffu)) * scale[c] + shift[c];
        float f1 = bf2f((unsigned short)(ua[j] >> 16)) * scale[c + 1] + shift[c + 1];
        f0 = fmaxf(f0, 0.f); f1 = fmaxf(f1, 0.f);
        ob[j] = (unsigned int)f2bf(f0) | ((unsigned int)f2bf(f1) << 16);
    }
    uint4 o = make_uint4(ob[0], ob[1], ob[2], ob[3]);
    *(uint4*)p = o;
}

// ---------------------------------------------------------------------------
// head conv: z [4][162][162][128] bf16 padded -> out [4][CO][160][160] fp32 (+bias)
// 1 position/thread, grid 400 blocks. Weights in LDS, wave-uniform broadcast reads.
template<int CO>
__global__ __launch_bounds__(256) void head_conv(const unsigned short* __restrict__ z,
                                                 const float* __restrict__ w,
                                                 const float* __restrict__ bias,
                                                 float* __restrict__ out) {
    __shared__ float s_w[CO * 9 * 128];
    for (int t = threadIdx.x; t < CO * 9 * 128; t += 256) {
        int ci = t % 128; int r = t / 128;
        int tap = r % 9;  int o = r / 9;
        s_w[t] = w[((size_t)(o * 128 + ci)) * 9 + tap];
    }
    __syncthreads();

    const int pos = blockIdx.x * 256 + threadIdx.x;   // 102400 exact
    const int pw = pos % 160, ph = (pos / 160) % 160, pn = pos / 25600;
    float acc[CO];
#pragma unroll
    for (int o = 0; o < CO; ++o) acc[o] = bias[o];

#pragma unroll
    for (int dh = 0; dh < 3; ++dh)
#pragma unroll
        for (int dw = 0; dw < 3; ++dw) {
            const int tap = dh * 3 + dw;
            const unsigned short* zp = z + ((size_t)((pn * 162 + ph + dh) * 162) + (pw + dw)) * 128;
            for (int c8 = 0; c8 < 16; ++c8) {
                uint4 v = *(const uint4*)(zp + c8 * 8);
                unsigned int ua[4] = {v.x, v.y, v.z, v.w};
                float xv[8];
#pragma unroll
                for (int j = 0; j < 4; ++j) {
                    xv[2 * j]     = bf2f((unsigned short)(ua[j] & 0xffffu));
                    xv[2 * j + 1] = bf2f((unsigned short)(ua[j] >> 16));
                }
#pragma unroll
                for (int o = 0; o < CO; ++o) {
                    const float* wp = &s_w[(o * 9 + tap) * 128 + c8 * 8];
                    float4 w0 = *(const float4*)wp;
                    float4 w1 = *(const float4*)(wp + 4);
                    acc[o] = fmaf(xv[0], w0.x, acc[o]);
                    acc[o] = fmaf(xv[1], w0.y, acc[o]);
                    acc[o] = fmaf(xv[2], w0.z, acc[o]);
                    acc[o] = fmaf(xv[3], w0.w, acc[o]);
                    acc[o] = fmaf(xv[4], w1.x, acc[o]);
                    acc[o] = fmaf(xv[5], w1.y, acc[o]);
                    acc[o] = fmaf(xv[6], w1.z, acc[o]);
                    acc[o] = fmaf(xv[7], w1.w, acc[o]);
                }
            }
        }
#pragma unroll
    for (int o = 0; o < CO; ++o)
        out[((size_t)(pn * CO + o)) * 25600 + ph * 160 + pw] = acc[o];
}

// ---------------------------------------------------------------------------
extern "C" void kernel_launch(void* const* d_in, const int* in_sizes, int n_in,
                              void* d_out, int out_size, void* d_ws, size_t ws_size,
                              hipStream_t stream) {
    const float* fpn = (const float*)d_in[0];
    const float* W1[3] = {(const float*)d_in[1],  (const float*)d_in[11], (const float*)d_in[19]};
    const float* G1[3] = {(const float*)d_in[2],  (const float*)d_in[12], (const float*)d_in[20]};
    const float* B1[3] = {(const float*)d_in[3],  (const float*)d_in[13], (const float*)d_in[21]};
    const float* W2[3] = {(const float*)d_in[4],  (const float*)d_in[14], (const float*)d_in[22]};
    const float* G2[3] = {(const float*)d_in[5],  (const float*)d_in[15], (const float*)d_in[23]};
    const float* B2[3] = {(const float*)d_in[6],  (const float*)d_in[16], (const float*)d_in[24]};
    const float* w_shrink = (const float*)d_in[7];  const float* b_shrink = (const float*)d_in[8];
    const float* w_cent   = (const float*)d_in[9];  const float* b_cent   = (const float*)d_in[10];
    const float* w_p3     = (const float*)d_in[17]; const float* b_p3     = (const float*)d_in[18];
    const float* w_s3     = (const float*)d_in[25]; const float* b_s3     = (const float*)d_in[26];
    float* out = (float*)d_out;

    char* ws = (char*)d_ws;
    size_t off = 0;
    unsigned short* xpad = (unsigned short*)(ws + off); off += (size_t)4 * 162 * 162 * 256 * 2;
    unsigned short* buf1 = (unsigned short*)(ws + off); off += (size_t)4 * 162 * 162 * 256 * 2;
    unsigned short* buf2 = (unsigned short*)(ws + off); off += (size_t)4 * 162 * 162 * 128 * 2;
    unsigned short* w1p  = (unsigned short*)(ws + off); off += (size_t)3 * 9 * 256 * 256 * 2;
    unsigned short* w2p  = (unsigned short*)(ws + off); off += (size_t)3 * 9 * 128 * 256 * 2;
    float* stats         = (float*)(ws + off);          off += (size_t)6 * 512 * 4;
    float* ssbuf         = (float*)(ws + off);          off += (size_t)6 * 512 * 4;

    hipMemsetAsync(stats, 0, 6 * 512 * 4, stream);
    zero_borders<<<(4 * 644 * 32 + 255) / 256, 256, 0, stream>>>(xpad, 256);
    zero_borders<<<(4 * 644 * 32 + 255) / 256, 256, 0, stream>>>(buf1, 256);
    zero_borders<<<(4 * 644 * 16 + 255) / 256, 256, 0, stream>>>(buf2, 128);
    transpose_pad<<<12800, 256, 0, stream>>>(fpn, xpad);
    for (int br = 0; br < 3; ++br) {
        pack_w<<<(9 * 256 * 256 + 255) / 256, 256, 0, stream>>>(W1[br], w1p + (size_t)br * 9 * 256 * 256, 256, 256);
        pack_w<<<(9 * 128 * 256 + 255) / 256, 256, 0, stream>>>(W2[br], w2p + (size_t)br * 9 * 128 * 256, 128, 256);
    }

    for (int br = 0; br < 3; ++br) {
        float* sum1 = stats + (size_t)(br * 2 + 0) * 512; float* sq1 = sum1 + 256;
        float* sum2 = stats + (size_t)(br * 2 + 1) * 512; float* sq2 = sum2 + 256;
        float* sc1 = ssbuf + (size_t)(br * 2 + 0) * 512;  float* sh1 = sc1 + 256;
        float* sc2 = ssbuf + (size_t)(br * 2 + 1) * 512;  float* sh2 = sc2 + 256;

        conv3x3_mfma<256, 256><<<1600, 256, 0, stream>>>(xpad, w1p + (size_t)br * 9 * 256 * 256,
                                                         buf1, sum1, sq1);
        bn_finalize<<<1, 256, 0, stream>>>(sum1, sq1, G1[br], B1[br], sc1, sh1, 256);
        bn_apply<256><<<12800, 256, 0, stream>>>(buf1, sc1, sh1);

        conv3x3_mfma<256, 128><<<800, 256, 0, stream>>>(buf1, w2p + (size_t)br * 9 * 128 * 256,
                                                        buf2, sum2, sq2);
        bn_finalize<<<1, 256, 0, stream>>>(sum2, sq2, G2[br], B2[br], sc2, sh2, 128);
        bn_apply<128><<<6400, 256, 0, stream>>>(buf2, sc2, sh2);

        if (br == 0) {
            head_conv<1><<<400, 256, 0, stream>>>(buf2, w_shrink, b_shrink, out);
            head_conv<1><<<400, 256, 0, stream>>>(buf2, w_cent, b_cent, out + 102400);
        } else if (br == 1) {
            head_conv<2><<<400, 256, 0, stream>>>(buf2, w_p3, b_p3, out + 204800);
        } else {
            head_conv<8><<<400, 256, 0, stream>>>(buf2, w_s3, b_s3, out + 409600);
        }
    }
}

// Round 3
// 2340.449 us; speedup vs baseline: 1.2474x; 1.2474x over previous
//
#include <hip/hip_runtime.h>

typedef short bf16x8 __attribute__((ext_vector_type(8)));
typedef float f32x4 __attribute__((ext_vector_type(4)));

__device__ __forceinline__ float bf2f(unsigned short u) {
    union { unsigned int i; float f; } c; c.i = ((unsigned int)u) << 16; return c.f;
}
__device__ __forceinline__ unsigned short f2bf(float f) {
    union { float f; unsigned int i; } c; c.f = f;
    unsigned int u = c.i;
    u += 0x7fffu + ((u >> 16) & 1u);          // round-to-nearest-even
    return (unsigned short)(u >> 16);
}

// async global->LDS, 16B per lane; LDS dest must be wave-uniform base + lane*16
__device__ __forceinline__ void gload_lds16(const unsigned short* g, unsigned short* l) {
    __builtin_amdgcn_global_load_lds(
        (const __attribute__((address_space(1))) void*)g,
        (__attribute__((address_space(3))) void*)l, 16, 0, 0);
}

// ---------------------------------------------------------------------------
// fpn fp32 NCHW [4][256][160][160] -> bf16 NHWC padded [4][162][162][256]
__global__ void transpose_pad(const float* __restrict__ x, unsigned short* __restrict__ xpad) {
    int idx = blockIdx.x * 256 + threadIdx.x;       // 4*160*160*32 = 3,276,800 exact
    int w = idx % 160; int t = idx / 160;
    int cv = t % 32;   t /= 32;
    int h = t % 160;   int n = t / 160;
    const float* src = x + (((size_t)(n * 256 + cv * 8) * 160 + h) * 160 + w);
    unsigned short us[8];
#pragma unroll
    for (int k = 0; k < 8; ++k) us[k] = f2bf(src[(size_t)k * 25600]);
    uint4 o;
    o.x = (unsigned int)us[0] | ((unsigned int)us[1] << 16);
    o.y = (unsigned int)us[2] | ((unsigned int)us[3] << 16);
    o.z = (unsigned int)us[4] | ((unsigned int)us[5] << 16);
    o.w = (unsigned int)us[6] | ((unsigned int)us[7] << 16);
    *(uint4*)(xpad + ((size_t)((n * 162 + h + 1) * 162) + (w + 1)) * 256 + cv * 8) = o;
}

// zero the 1-wide border of a padded NHWC buffer [4][162][162][C]
__global__ void zero_borders(unsigned short* __restrict__ buf, int C) {
    int CV = C >> 3;
    int total = 4 * 644 * CV;
    int idx = blockIdx.x * 256 + threadIdx.x;
    if (idx >= total) return;
    int cv = idx % CV; int t = idx / CV;
    int p = t % 644;   int n = t / 644;
    int h, w;
    if (p < 162)      { h = 0;   w = p; }
    else if (p < 324) { h = 161; w = p - 162; }
    else { int q = p - 324; h = 1 + (q >> 1); w = (q & 1) ? 161 : 0; }
    uint4 z = make_uint4(0u, 0u, 0u, 0u);
    *(uint4*)(buf + ((size_t)((n * 162 + h) * 162) + w) * C + cv * 8) = z;
}

// w fp32 OIHW [CO][CI][3][3] -> bf16 [tap][CO][CI]
__global__ void pack_w(const float* __restrict__ w, unsigned short* __restrict__ out, int CO, int CI) {
    int idx = blockIdx.x * 256 + threadIdx.x;
    int tot = 9 * CO * CI;
    if (idx >= tot) return;
    int ci = idx % CI; int t = idx / CI;
    int co = t % CO;   int tap = t / CO;
    out[idx] = f2bf(w[((size_t)(co * CI + ci)) * 9 + tap]);
}

// ---------------------------------------------------------------------------
// 3x3 conv, implicit GEMM, bf16 MFMA 16x16x32.
// Round-1 window structure (A 16KB + B 16KB staged per window, 32 MFMAs
// between 2 barriers, 32KB LDS) with staging swapped to async
// global_load_lds width=16 (the m93->m97 lever). Taps fully unrolled so
// dh/dw are compile-time; ci-chunk loop runtime. XOR-16B swizzle folded
// into the global source address (0 bank conflicts, DMA-compatible layout).
template<int CI, int COT>
__global__ __launch_bounds__(256) void conv3x3_mfma(
        const unsigned short* __restrict__ xpad,
        const unsigned short* __restrict__ wpk,
        unsigned short* __restrict__ ypad,
        float* __restrict__ sum, float* __restrict__ sumsq) {
    __shared__ __align__(16) unsigned short As[128 * 64];
    __shared__ __align__(16) unsigned short Bs[128 * 64];

    const int tid = threadIdx.x;
    const int wv = tid >> 6, lane = tid & 63;
    const int quad = lane >> 4, l15 = lane & 15;
    const int wr = wv >> 1, wc = wv & 1;

    int bid = blockIdx.x;
    const int wt = bid % 5;  bid /= 5;
    const int ht = bid % 40; bid /= 40;
    const int n = bid % 4;
    const int co0 = (bid / 4) * 128;
    const int h0 = ht * 4, w0 = wt * 32;   // tile origin in padded coords

    f32x4 acc[4][4];
#pragma unroll
    for (int i = 0; i < 4; ++i)
#pragma unroll
        for (int j = 0; j < 4; ++j) acc[i][j] = (f32x4){0.f, 0.f, 0.f, 0.f};

#pragma unroll
    for (int dh = 0; dh < 3; ++dh) {
#pragma unroll
        for (int dw = 0; dw < 3; ++dw) {
            const int tap = dh * 3 + dw;
            const unsigned short* wbase = wpk + ((size_t)(tap * COT + co0)) * CI;
            const unsigned short* xbase = xpad +
                ((size_t)((n * 162 + h0 + dh) * 162) + (w0 + dw)) * CI;
            for (int ci0 = 0; ci0 < CI; ci0 += 64) {
                __syncthreads();   // previous window's LDS reads complete
#pragma unroll
                for (int c = 0; c < 4; ++c) {
                    const int f = c * 4096 + tid * 16;       // byte offset in As
                    const int row = f >> 7;
                    const int g = ((f >> 4) & 7) ^ (row & 7);
                    gload_lds16(wbase + (size_t)row * CI + ci0 + g * 8,
                                (unsigned short*)As + (f >> 1));
                }
#pragma unroll
                for (int c = 0; c < 4; ++c) {
                    const int f = c * 4096 + tid * 16;       // byte offset in Bs
                    const int row = f >> 7;
                    const int jh = row >> 5, jw = row & 31;
                    const int g = ((f >> 4) & 7) ^ (row & 7);
                    gload_lds16(xbase + ((size_t)(jh * 162 + jw)) * CI + ci0 + g * 8,
                                (unsigned short*)Bs + (f >> 1));
                }
                __syncthreads();   // drains vmcnt: tiles ready
#pragma unroll
                for (int s = 0; s < 2; ++s) {
                    const int g0 = s * 4 + quad;
                    bf16x8 a[4], b[4];
#pragma unroll
                    for (int i = 0; i < 4; ++i) {
                        int row = wr * 64 + i * 16 + l15;
                        a[i] = *(const bf16x8*)&As[row * 64 + ((g0 ^ (row & 7)) << 3)];
                    }
#pragma unroll
                    for (int j = 0; j < 4; ++j) {
                        int row = wc * 64 + j * 16 + l15;
                        b[j] = *(const bf16x8*)&Bs[row * 64 + ((g0 ^ (row & 7)) << 3)];
                    }
#pragma unroll
                    for (int i = 0; i < 4; ++i)
#pragma unroll
                        for (int j = 0; j < 4; ++j)
                            acc[i][j] = __builtin_amdgcn_mfma_f32_16x16x32_bf16(a[i], b[j], acc[i][j], 0, 0, 0);
                }
            }
        }
    }

    // epilogue: store y (bf16, NHWC padded interior) + BN partial stats
#pragma unroll
    for (int i = 0; i < 4; ++i) {
        const int co_l = wr * 64 + i * 16 + quad * 4;
#pragma unroll
        for (int j = 0; j < 4; ++j) {
            const int sp = wc * 64 + j * 16 + l15;
            const int jh = sp >> 5, jw = sp & 31;
            f32x4 v = acc[i][j];
            ushort4 pk;
            pk.x = f2bf(v[0]); pk.y = f2bf(v[1]); pk.z = f2bf(v[2]); pk.w = f2bf(v[3]);
            *(ushort4*)(ypad + ((size_t)((n * 162 + h0 + jh + 1) * 162) + (w0 + jw + 1)) * COT
                        + co0 + co_l) = pk;
        }
#pragma unroll
        for (int r = 0; r < 4; ++r) {
            float s1 = 0.f, s2 = 0.f;
#pragma unroll
            for (int j = 0; j < 4; ++j) { float v = acc[i][j][r]; s1 += v; s2 += v * v; }
#pragma unroll
            for (int m = 1; m < 16; m <<= 1) {
                s1 += __shfl_xor(s1, m, 64);
                s2 += __shfl_xor(s2, m, 64);
            }
            if (l15 == 0) {
                atomicAdd(&sum[co0 + co_l + r], s1);
                atomicAdd(&sumsq[co0 + co_l + r], s2);
            }
        }
    }
}

// ---------------------------------------------------------------------------
__global__ void bn_finalize(const float* __restrict__ sum, const float* __restrict__ sumsq,
                            const float* __restrict__ g, const float* __restrict__ b,
                            float* __restrict__ scale, float* __restrict__ shift, int C) {
    int c = blockIdx.x * 256 + threadIdx.x;
    if (c >= C) return;
    const float inv = 1.0f / 102400.0f;
    float m = sum[c] * inv;
    float v = sumsq[c] * inv - m * m;
    float sc = g[c] * rsqrtf(v + 1e-5f);
    scale[c] = sc;
    shift[c] = b[c] - m * sc;
}

// in-place y := relu(y*scale[c]+shift[c]) over the interior of padded NHWC buf
template<int C>
__global__ void bn_apply(unsigned short* __restrict__ buf,
                         const float* __restrict__ scale, const float* __restrict__ shift) {
    constexpr int CV = C / 8;
    int idx = blockIdx.x * 256 + threadIdx.x;       // 4*25600*CV exact
    int cv = idx % CV; int pos = idx / CV;
    int w = pos % 160; int h = (pos / 160) % 160; int n = pos / 25600;
    unsigned short* p = buf + ((size_t)((n * 162 + h + 1) * 162) + (w + 1)) * C + cv * 8;
    uint4 v = *(const uint4*)p;
    unsigned int ua[4] = {v.x, v.y, v.z, v.w};
    unsigned int ob[4];
#pragma unroll
    for (int j = 0; j < 4; ++j) {
        int c = cv * 8 + j * 2;
        float f0 = bf2f((unsigned short)(ua[j] & 0xffffu)) * scale[c] + shift[c];
        float f1 = bf2f((unsigned short)(ua[j] >> 16)) * scale[c + 1] + shift[c + 1];
        f0 = fmaxf(f0, 0.f); f1 = fmaxf(f1, 0.f);
        ob[j] = (unsigned int)f2bf(f0) | ((unsigned int)f2bf(f1) << 16);
    }
    uint4 o = make_uint4(ob[0], ob[1], ob[2], ob[3]);
    *(uint4*)p = o;
}

// ---------------------------------------------------------------------------
// head conv: z [4][162][162][128] bf16 padded -> out [4][CO][160][160] fp32 (+bias)
// 1 position/thread, grid 400 blocks. Weights in LDS, wave-uniform broadcast reads.
template<int CO>
__global__ __launch_bounds__(256) void head_conv(const unsigned short* __restrict__ z,
                                                 const float* __restrict__ w,
                                                 const float* __restrict__ bias,
                                                 float* __restrict__ out) {
    __shared__ float s_w[CO * 9 * 128];
    for (int t = threadIdx.x; t < CO * 9 * 128; t += 256) {
        int ci = t % 128; int r = t / 128;
        int tap = r % 9;  int o = r / 9;
        s_w[t] = w[((size_t)(o * 128 + ci)) * 9 + tap];
    }
    __syncthreads();

    const int pos = blockIdx.x * 256 + threadIdx.x;   // 102400 exact
    const int pw = pos % 160, ph = (pos / 160) % 160, pn = pos / 25600;
    float acc[CO];
#pragma unroll
    for (int o = 0; o < CO; ++o) acc[o] = bias[o];

#pragma unroll
    for (int dh = 0; dh < 3; ++dh)
#pragma unroll
        for (int dw = 0; dw < 3; ++dw) {
            const int tap = dh * 3 + dw;
            const unsigned short* zp = z + ((size_t)((pn * 162 + ph + dh) * 162) + (pw + dw)) * 128;
            for (int c8 = 0; c8 < 16; ++c8) {
                uint4 v = *(const uint4*)(zp + c8 * 8);
                unsigned int ua[4] = {v.x, v.y, v.z, v.w};
                float xv[8];
#pragma unroll
                for (int j = 0; j < 4; ++j) {
                    xv[2 * j]     = bf2f((unsigned short)(ua[j] & 0xffffu));
                    xv[2 * j + 1] = bf2f((unsigned short)(ua[j] >> 16));
                }
#pragma unroll
                for (int o = 0; o < CO; ++o) {
                    const float* wp = &s_w[(o * 9 + tap) * 128 + c8 * 8];
                    float4 w0 = *(const float4*)wp;
                    float4 w1 = *(const float4*)(wp + 4);
                    acc[o] = fmaf(xv[0], w0.x, acc[o]);
                    acc[o] = fmaf(xv[1], w0.y, acc[o]);
                    acc[o] = fmaf(xv[2], w0.z, acc[o]);
                    acc[o] = fmaf(xv[3], w0.w, acc[o]);
                    acc[o] = fmaf(xv[4], w1.x, acc[o]);
                    acc[o] = fmaf(xv[5], w1.y, acc[o]);
                    acc[o] = fmaf(xv[6], w1.z, acc[o]);
                    acc[o] = fmaf(xv[7], w1.w, acc[o]);
                }
            }
        }
#pragma unroll
    for (int o = 0; o < CO; ++o)
        out[((size_t)(pn * CO + o)) * 25600 + ph * 160 + pw] = acc[o];
}

// ---------------------------------------------------------------------------
extern "C" void kernel_launch(void* const* d_in, const int* in_sizes, int n_in,
                              void* d_out, int out_size, void* d_ws, size_t ws_size,
                              hipStream_t stream) {
    const float* fpn = (const float*)d_in[0];
    const float* W1[3] = {(const float*)d_in[1],  (const float*)d_in[11], (const float*)d_in[19]};
    const float* G1[3] = {(const float*)d_in[2],  (const float*)d_in[12], (const float*)d_in[20]};
    const float* B1[3] = {(const float*)d_in[3],  (const float*)d_in[13], (const float*)d_in[21]};
    const float* W2[3] = {(const float*)d_in[4],  (const float*)d_in[14], (const float*)d_in[22]};
    const float* G2[3] = {(const float*)d_in[5],  (const float*)d_in[15], (const float*)d_in[23]};
    const float* B2[3] = {(const float*)d_in[6],  (const float*)d_in[16], (const float*)d_in[24]};
    const float* w_shrink = (const float*)d_in[7];  const float* b_shrink = (const float*)d_in[8];
    const float* w_cent   = (const float*)d_in[9];  const float* b_cent   = (const float*)d_in[10];
    const float* w_p3     = (const float*)d_in[17]; const float* b_p3     = (const float*)d_in[18];
    const float* w_s3     = (const float*)d_in[25]; const float* b_s3     = (const float*)d_in[26];
    float* out = (float*)d_out;

    char* ws = (char*)d_ws;
    size_t off = 0;
    unsigned short* xpad = (unsigned short*)(ws + off); off += (size_t)4 * 162 * 162 * 256 * 2;
    unsigned short* buf1 = (unsigned short*)(ws + off); off += (size_t)4 * 162 * 162 * 256 * 2;
    unsigned short* buf2 = (unsigned short*)(ws + off); off += (size_t)4 * 162 * 162 * 128 * 2;
    unsigned short* w1p  = (unsigned short*)(ws + off); off += (size_t)3 * 9 * 256 * 256 * 2;
    unsigned short* w2p  = (unsigned short*)(ws + off); off += (size_t)3 * 9 * 128 * 256 * 2;
    float* stats         = (float*)(ws + off);          off += (size_t)6 * 512 * 4;
    float* ssbuf         = (float*)(ws + off);          off += (size_t)6 * 512 * 4;

    hipMemsetAsync(stats, 0, 6 * 512 * 4, stream);
    zero_borders<<<(4 * 644 * 32 + 255) / 256, 256, 0, stream>>>(xpad, 256);
    zero_borders<<<(4 * 644 * 32 + 255) / 256, 256, 0, stream>>>(buf1, 256);
    zero_borders<<<(4 * 644 * 16 + 255) / 256, 256, 0, stream>>>(buf2, 128);
    transpose_pad<<<12800, 256, 0, stream>>>(fpn, xpad);
    for (int br = 0; br < 3; ++br) {
        pack_w<<<(9 * 256 * 256 + 255) / 256, 256, 0, stream>>>(W1[br], w1p + (size_t)br * 9 * 256 * 256, 256, 256);
        pack_w<<<(9 * 128 * 256 + 255) / 256, 256, 0, stream>>>(W2[br], w2p + (size_t)br * 9 * 128 * 256, 128, 256);
    }

    for (int br = 0; br < 3; ++br) {
        float* sum1 = stats + (size_t)(br * 2 + 0) * 512; float* sq1 = sum1 + 256;
        float* sum2 = stats + (size_t)(br * 2 + 1) * 512; float* sq2 = sum2 + 256;
        float* sc1 = ssbuf + (size_t)(br * 2 + 0) * 512;  float* sh1 = sc1 + 256;
        float* sc2 = ssbuf + (size_t)(br * 2 + 1) * 512;  float* sh2 = sc2 + 256;

        conv3x3_mfma<256, 256><<<1600, 256, 0, stream>>>(xpad, w1p + (size_t)br * 9 * 256 * 256,
                                                         buf1, sum1, sq1);
        bn_finalize<<<1, 256, 0, stream>>>(sum1, sq1, G1[br], B1[br], sc1, sh1, 256);
        bn_apply<256><<<12800, 256, 0, stream>>>(buf1, sc1, sh1);

        conv3x3_mfma<256, 128><<<800, 256, 0, stream>>>(buf1, w2p + (size_t)br * 9 * 128 * 256,
                                                        buf2, sum2, sq2);
        bn_finalize<<<1, 256, 0, stream>>>(sum2, sq2, G2[br], B2[br], sc2, sh2, 128);
        bn_apply<128><<<6400, 256, 0, stream>>>(buf2, sc2, sh2);

        if (br == 0) {
            head_conv<1><<<400, 256, 0, stream>>>(buf2, w_shrink, b_shrink, out);
            head_conv<1><<<400, 256, 0, stream>>>(buf2, w_cent, b_cent, out + 102400);
        } else if (br == 1) {
            head_conv<2><<<400, 256, 0, stream>>>(buf2, w_p3, b_p3, out + 204800);
        } else {
            head_conv<8><<<400, 256, 0, stream>>>(buf2, w_s3, b_s3, out + 409600);
        }
    }
}